// Round 10
// baseline (735.005 us; speedup 1.0000x reference)
//
#include <hip/hip_runtime.h>
#include <math.h>

#define HC     128    // HEADS*OUT_CH
#define SLOT   64     // bucket row stride = max(in-deg+1); Poisson(16): P(>63) ~ 5e-19
#define AGG_BLOCKS 2048
#define CAP    4608   // coarse-bucket capacity: mean 4096 + 8 sigma
#define BSH    8      // 256 nodes per coarse bucket

typedef unsigned int uint32;
typedef unsigned long long uint64;
typedef short bf16x8 __attribute__((ext_vector_type(8)));
typedef float f32x4 __attribute__((ext_vector_type(4)));
typedef int   i32x4 __attribute__((ext_vector_type(4)));

__device__ inline unsigned short f2bf(float f){
  uint32 u = __float_as_uint(f);
  u = (u + 0x7fffu + ((u >> 16) & 1u)) >> 16;
  return (unsigned short)u;
}
__device__ inline uint32 pack_bf2(float a, float b){
  return (uint32)f2bf(a) | ((uint32)f2bf(b) << 16);
}
// intra-wave LDS ordering (wave-private slices; no cross-wave barrier needed)
__device__ inline void lds_fence(){
  asm volatile("s_waitcnt lgkmcnt(0)" ::: "memory");
  __builtin_amdgcn_sched_barrier(0);
}

// ---------------- init: zero coarse cursors + convert W to bf16 ----------------

__global__ __launch_bounds__(256) void k_init(const float* __restrict__ W, unsigned short* __restrict__ W_bf,
                                              int* pcnt, int NB){
  int gid = blockIdx.x*256 + threadIdx.x;
  if (gid < 8192){                                 // 16384 W elems, 2 per thread
    float2 v = *(const float2*)&W[2*gid];
    *(uint32*)&W_bf[2*gid] = pack_bf2(v.x, v.y);
  }
  if (gid < NB) pcnt[gid] = 0;
}

// ---------------- radix phase 1: append edges to coarse dest-buckets ----------------
// entry = (d&255)<<17 | src  (src < 2^17). Consecutive atomic winners write
// consecutive 4B slots -> 64B lines fill while resident (no scatter amplification).

__global__ __launch_bounds__(256) void k_part(const int* __restrict__ row, const int* __restrict__ col,
                                              int* pcnt, uint32* __restrict__ pbuf, int E){
  int gid = blockIdx.x*256 + threadIdx.x;
  int i = gid*4;
  if (i + 4 <= E){
    i32x4 r4 = __builtin_nontemporal_load((const i32x4*)&row[i]);
    i32x4 c4 = __builtin_nontemporal_load((const i32x4*)&col[i]);
    #pragma unroll
    for (int q = 0; q < 4; ++q){
      int d = r4[q], s = c4[q];
      int b = d >> BSH;
      int pos = atomicAdd(&pcnt[b], 1);
      if (pos < CAP) pbuf[(size_t)b*CAP + pos] = ((uint32)(d & 255) << 17) | (uint32)s;
    }
  } else {
    for (; i < E; ++i){
      int d = row[i], s = col[i];
      int b = d >> BSH;
      int pos = atomicAdd(&pcnt[b], 1);
      if (pos < CAP) pbuf[(size_t)b*CAP + pos] = ((uint32)(d & 255) << 17) | (uint32)s;
    }
  }
}

// ---------------- radix phase 2: per-bucket LDS-cursor scatter (L2-resident 64KB region) ----------------

__global__ __launch_bounds__(256) void k_scatter(const int* __restrict__ pcnt, const uint32* __restrict__ pbuf,
                                                 int* __restrict__ cnt, int* __restrict__ bucket, int N){
  __shared__ int lcnt[256];
  int t = threadIdx.x;
  int b = blockIdx.x;
  lcnt[t] = 0;
  __syncthreads();
  int ne = pcnt[b]; if (ne > CAP) ne = CAP;
  int dbase = b << BSH;
  for (int i = t; i < ne; i += 256){
    uint32 e = __builtin_nontemporal_load(&pbuf[(size_t)b*CAP + i]);
    int s  = (int)(e & 0x1FFFFu);
    int dl = (int)(e >> 17);
    int pos = atomicAdd(&lcnt[dl], 1);
    if (pos < SLOT-1) bucket[(size_t)(dbase + dl)*SLOT + pos] = s;
  }
  __syncthreads();
  int d = dbase + t;
  if (d < N) cnt[d] = lcnt[t];
}

// ---------------- zero-LDS MFMA GEMM (bf16): W_bf from global (L1-hot), x NT ----------------
// 64-node tile, 4 waves x 16 rows. h_pair[n][hd*16+o] packs channels (32hd+o, 32hd+16+o).

__global__ __launch_bounds__(256) void k_gemm(const float* __restrict__ x, const unsigned short* __restrict__ W_bf,
                                              const float* __restrict__ att,
                                              uint32* __restrict__ h_pair,
                                              float* __restrict__ s_i, float* __restrict__ s_j, int N){
  int t = threadIdx.x;
  int w = t >> 6, l = t & 63;
  int o = l & 15, lg = l >> 4;
  int n0 = blockIdx.x * 64;

  int arow = n0 + w*16 + o;
  bool rok = (arow < N);
  const float* xr = x + (size_t)arow*128;
  bf16x8 afr[4];
  #pragma unroll
  for (int ks = 0; ks < 4; ++ks){
    f32x4 a0 = (f32x4){0.f,0.f,0.f,0.f}, a1 = a0;
    if (rok){
      a0 = __builtin_nontemporal_load((const f32x4*)&xr[ks*32 + lg*8]);
      a1 = __builtin_nontemporal_load((const f32x4*)&xr[ks*32 + lg*8 + 4]);
    }
    bf16x8 pa;
    pa[0]=(short)f2bf(a0[0]); pa[1]=(short)f2bf(a0[1]); pa[2]=(short)f2bf(a0[2]); pa[3]=(short)f2bf(a0[3]);
    pa[4]=(short)f2bf(a1[0]); pa[5]=(short)f2bf(a1[1]); pa[6]=(short)f2bf(a1[2]); pa[7]=(short)f2bf(a1[3]);
    afr[ks] = pa;
  }

  f32x4 acc[8];
  #pragma unroll
  for (int cf = 0; cf < 8; ++cf) acc[cf] = (f32x4){0.f,0.f,0.f,0.f};

  #pragma unroll
  for (int ks = 0; ks < 4; ++ks){
    #pragma unroll
    for (int cf = 0; cf < 8; ++cf){
      int rb = cf*16 + o;
      bf16x8 bfr = *(const bf16x8*)&W_bf[(size_t)rb*128 + ks*32 + lg*8];
      acc[cf] = __builtin_amdgcn_mfma_f32_16x16x32_bf16(afr[ks], bfr, acc[cf], 0, 0, 0);
    }
  }

  float ai0[4], ai1[4], aj0[4], aj1[4];
  #pragma unroll
  for (int hd = 0; hd < 4; ++hd){
    ai0[hd] = att[hd*64 + o];
    ai1[hd] = att[hd*64 + 16 + o];
    aj0[hd] = att[hd*64 + 32 + o];
    aj1[hd] = att[hd*64 + 48 + o];
  }

  // epilogue: D row = w*16 + lg*4 + q, col = cf*16 + o
  #pragma unroll
  for (int q = 0; q < 4; ++q){
    int node = n0 + w*16 + lg*4 + q;
    float v[8];
    #pragma unroll
    for (int cf = 0; cf < 8; ++cf) v[cf] = acc[cf][q];
    float pi[4], pj[4];
    #pragma unroll
    for (int hd = 0; hd < 4; ++hd){
      pi[hd] = v[2*hd]*ai0[hd] + v[2*hd+1]*ai1[hd];
      pj[hd] = v[2*hd]*aj0[hd] + v[2*hd+1]*aj1[hd];
    }
    #pragma unroll
    for (int sh = 1; sh < 16; sh <<= 1){
      #pragma unroll
      for (int hd = 0; hd < 4; ++hd){
        pi[hd] += __shfl_xor(pi[hd], sh);
        pj[hd] += __shfl_xor(pj[hd], sh);
      }
    }
    if (node < N){
      #pragma unroll
      for (int hd = 0; hd < 4; ++hd)
        __builtin_nontemporal_store(pack_bf2(v[2*hd], v[2*hd+1]),
                                    &h_pair[(size_t)node*64 + hd*16 + o]);
      if (o == 0){
        f32x4 vi = (f32x4){pi[0], pi[1], pi[2], pi[3]};
        f32x4 vj = (f32x4){pj[0], pj[1], pj[2], pj[3]};
        __builtin_nontemporal_store(vi, (f32x4*)&s_i[(size_t)node*4]);
        __builtin_nontemporal_store(vj, (f32x4*)&s_j[(size_t)node*4]);
      }
    }
  }
}

// ---------------- fused softmax + gram + weighted aggregation (independent wave per node) ----------------

__global__ __launch_bounds__(256) void k_agg(const uint32* __restrict__ h_pair, const float* __restrict__ s_i,
                                             const float* __restrict__ s_j, const int* __restrict__ cnt,
                                             const int* __restrict__ bucket,
                                             const float* __restrict__ bias, float* __restrict__ out,
                                             float* __restrict__ gram_part, int N){
  __shared__ __align__(16) float al[4][SLOT*4];   // per-wave alpha[j][head]
  __shared__ int   cs[4][SLOT];                   // per-wave src*32 (uint2 row offset)
  __shared__ float red[4][10];
  const uint2* hp2 = (const uint2*)h_pair;
  int t = threadIdx.x;
  int w = t >> 6, l = t & 63;
  int g = l >> 4, o = l & 15;        // softmax mapping
  int lw = l & 31, half = l >> 5;    // gather mapping
  int g2 = lw >> 3;
  int o0 = (2*lw) & 15;
  int cbase = 32*g2 + (half << 4) + o0;
  float2 bv = *(const float2*)&bias[cbase];
  float ga[10];
  #pragma unroll
  for (int p = 0; p < 10; ++p) ga[p] = 0.f;
  int TW = gridDim.x * 4;

  for (int n = blockIdx.x*4 + w; n < N; n += TW){
    int dc = cnt[n]; if (dc > SLOT-1) dc = SLOT-1;
    int d  = dc + 1;                               // + self loop (implicit, last slot)
    float4 si = *(const float4*)&s_i[(size_t)n*4];
    if (l < d){
      int src = (l < dc) ? __builtin_nontemporal_load(&bucket[(size_t)n*SLOT + l]) : n;
      cs[w][l] = src << 5;                         // uint2 row offset
      float4 sj = *(const float4*)&s_j[(size_t)src*4];
      float4 e;
      e.x = si.x + sj.x; e.y = si.y + sj.y; e.z = si.z + sj.z; e.w = si.w + sj.w;
      e.x = e.x >= 0.f ? e.x : 0.2f*e.x;
      e.y = e.y >= 0.f ? e.y : 0.2f*e.y;
      e.z = e.z >= 0.f ? e.z : 0.2f*e.z;
      e.w = e.w >= 0.f ? e.w : 0.2f*e.w;
      *(float4*)&al[w][l*4] = e;
    }
    if ((d & 1) && l == d){                        // pad edge for odd d: alpha 0, valid addr
      cs[w][l] = n << 5;
      *(float4*)&al[w][l*4] = make_float4(0.f,0.f,0.f,0.f);
    }
    lds_fence();
    float m = -3.4e38f;
    for (int j = o; j < d; j += 16) m = fmaxf(m, al[w][j*4 + g]);
    #pragma unroll
    for (int sh = 1; sh < 16; sh <<= 1) m = fmaxf(m, __shfl_xor(m, sh));
    float sum = 0.f;
    for (int j = o; j < d; j += 16){
      float v = __expf(al[w][j*4 + g] - m);
      al[w][j*4 + g] = v;
      sum += v;
    }
    #pragma unroll
    for (int sh = 1; sh < 16; sh <<= 1) sum += __shfl_xor(sum, sh);
    float r = 1.f/(sum + 1e-16f);
    for (int j = o; j < d; j += 16) al[w][j*4 + g] *= r;
    lds_fence();
    if (l < d){
      float4 a = *(const float4*)&al[w][l*4];
      ga[0] += a.x*a.x; ga[1] += a.x*a.y; ga[2] += a.x*a.z; ga[3] += a.x*a.w;
      ga[4] += a.y*a.y; ga[5] += a.y*a.z; ga[6] += a.y*a.w;
      ga[7] += a.z*a.z; ga[8] += a.z*a.w;
      ga[9] += a.w*a.w;
    }
    // half-wave gather: two edges per iteration across the wave, 4-deep unroll
    float a0 = 0.f, a1 = 0.f, a2 = 0.f, a3 = 0.f;
    const float* alw = &al[w][0];
    const int*   csw = &cs[w][0];
    int npair = (d + 1) >> 1;
    int i = 0;
    for (; i + 4 <= npair; i += 4){
      int e0 = 2*i + half, e1 = e0 + 2, e2 = e0 + 4, e3 = e0 + 6;
      int s0 = csw[e0], s1 = csw[e1], s2 = csw[e2], s3 = csw[e3];
      float w0 = alw[e0*4 + g2], w1 = alw[e1*4 + g2];
      float w2 = alw[e2*4 + g2], w3 = alw[e3*4 + g2];
      uint2 v0 = hp2[(size_t)(uint32)(s0 + lw)];
      uint2 v1 = hp2[(size_t)(uint32)(s1 + lw)];
      uint2 v2 = hp2[(size_t)(uint32)(s2 + lw)];
      uint2 v3 = hp2[(size_t)(uint32)(s3 + lw)];
      a0 += w0 * __uint_as_float(v0.x << 16);  a1 += w0 * __uint_as_float(v0.x & 0xffff0000u);
      a2 += w0 * __uint_as_float(v0.y << 16);  a3 += w0 * __uint_as_float(v0.y & 0xffff0000u);
      a0 += w1 * __uint_as_float(v1.x << 16);  a1 += w1 * __uint_as_float(v1.x & 0xffff0000u);
      a2 += w1 * __uint_as_float(v1.y << 16);  a3 += w1 * __uint_as_float(v1.y & 0xffff0000u);
      a0 += w2 * __uint_as_float(v2.x << 16);  a1 += w2 * __uint_as_float(v2.x & 0xffff0000u);
      a2 += w2 * __uint_as_float(v2.y << 16);  a3 += w2 * __uint_as_float(v2.y & 0xffff0000u);
      a0 += w3 * __uint_as_float(v3.x << 16);  a1 += w3 * __uint_as_float(v3.x & 0xffff0000u);
      a2 += w3 * __uint_as_float(v3.y << 16);  a3 += w3 * __uint_as_float(v3.y & 0xffff0000u);
    }
    for (; i < npair; ++i){
      int e = 2*i + half;
      float aw = alw[e*4 + g2];
      uint2 v = hp2[(size_t)(uint32)(csw[e] + lw)];
      a0 += aw * __uint_as_float(v.x << 16);  a1 += aw * __uint_as_float(v.x & 0xffff0000u);
      a2 += aw * __uint_as_float(v.y << 16);  a3 += aw * __uint_as_float(v.y & 0xffff0000u);
    }
    a0 += __shfl_xor(a0, 32);
    a1 += __shfl_xor(a1, 32);
    a2 += __shfl_xor(a2, 32);
    a3 += __shfl_xor(a3, 32);
    union { float f[2]; uint64 u; } st;
    st.f[0] = (half ? a1 : a0) + bv.x;
    st.f[1] = (half ? a3 : a2) + bv.y;
    __builtin_nontemporal_store(st.u, (uint64*)&out[(size_t)n*128 + cbase]);
    lds_fence();                                   // WAR guard before next staging write
  }
  __syncthreads();
  #pragma unroll
  for (int p = 0; p < 10; ++p){
    float v = ga[p];
    #pragma unroll
    for (int sh = 1; sh < 64; sh <<= 1) v += __shfl_xor(v, sh);
    ga[p] = v;
  }
  if (l == 0){
    #pragma unroll
    for (int p = 0; p < 10; ++p) red[w][p] = ga[p];
  }
  __syncthreads();
  if (t == 0){
    #pragma unroll
    for (int p = 0; p < 10; ++p)
      gram_part[(size_t)blockIdx.x*10 + p] = red[0][p] + red[1][p] + red[2][p] + red[3][p];
  }
}

// ---------------- gram reduce + diversity loss ----------------

__global__ __launch_bounds__(256) void k_final(const float* __restrict__ gram_part, int nparts,
                                               float* __restrict__ loss){
  __shared__ float red[4][10];
  int t = threadIdx.x;
  float acc[10];
  #pragma unroll
  for (int p = 0; p < 10; ++p) acc[p] = 0.f;
  for (int i = t; i < nparts; i += 256){
    #pragma unroll
    for (int p = 0; p < 10; ++p) acc[p] += gram_part[(size_t)i*10 + p];
  }
  #pragma unroll
  for (int p = 0; p < 10; ++p){
    float v = acc[p];
    #pragma unroll
    for (int sh = 1; sh < 64; sh <<= 1) v += __shfl_xor(v, sh);
    acc[p] = v;
  }
  if ((t & 63) == 0){
    #pragma unroll
    for (int p = 0; p < 10; ++p) red[t >> 6][p] = acc[p];
  }
  __syncthreads();
  if (t == 0){
    float gs[10];
    #pragma unroll
    for (int p = 0; p < 10; ++p) gs[p] = red[0][p] + red[1][p] + red[2][p] + red[3][p];
    float G[4][4];
    G[0][0]=gs[0]; G[0][1]=gs[1]; G[0][2]=gs[2]; G[0][3]=gs[3];
    G[1][0]=gs[1]; G[1][1]=gs[4]; G[1][2]=gs[5]; G[1][3]=gs[6];
    G[2][0]=gs[2]; G[2][1]=gs[5]; G[2][2]=gs[7]; G[2][3]=gs[8];
    G[3][0]=gs[3]; G[3][1]=gs[6]; G[3][2]=gs[8]; G[3][3]=gs[9];
    float nr[4];
    for (int i = 0; i < 4; ++i) nr[i] = sqrtf(G[i][i]);
    float ssum = 0.f;
    for (int i = 0; i < 4; ++i)
      for (int j = 0; j < 4; ++j)
        if (i != j) ssum += G[i][j] / fmaxf(nr[i]*nr[j], 1e-8f);
    loss[0] = ssum * (0.1f/16.f);
  }
}

// ---------------- launch ----------------

extern "C" void kernel_launch(void* const* d_in, const int* in_sizes, int n_in,
                              void* d_out, int out_size, void* d_ws, size_t ws_size,
                              hipStream_t stream){
  const float* x    = (const float*)d_in[0];
  const int*   edge = (const int*)d_in[1];
  const float* W    = (const float*)d_in[2];
  const float* att  = (const float*)d_in[3];
  const float* bias = (const float*)d_in[4];
  int N = in_sizes[0] / 128;
  int E = in_sizes[1] / 2;
  const int* row = edge;       // destinations
  const int* col = edge + E;   // sources
  float* out  = (float*)d_out;
  float* loss = out + (size_t)N*HC;

  int NB = (N + 255) >> BSH;   // coarse buckets (256 nodes each)

  char* wsb = (char*)d_ws;
  size_t off = 0;
  auto alloc = [&](size_t bytes)->void*{
    size_t o = (off + 255) & ~(size_t)255;
    off = o + bytes;
    return (void*)(wsb + o);
  };
  uint32* h_pair   = (uint32*)alloc((size_t)N*64*sizeof(uint32));
  float* s_i       = (float*)alloc((size_t)N*4*sizeof(float));
  float* s_j       = (float*)alloc((size_t)N*4*sizeof(float));
  int*   cnt       = (int*)alloc((size_t)N*sizeof(int));
  int*   bucket    = (int*)alloc((size_t)N*SLOT*sizeof(int));
  int*   pcnt      = (int*)alloc((size_t)NB*sizeof(int));
  uint32* pbuf     = (uint32*)alloc((size_t)NB*CAP*sizeof(uint32));
  unsigned short* W_bf = (unsigned short*)alloc(16384*sizeof(unsigned short));
  float* gram_part = (float*)alloc((size_t)AGG_BLOCKS*10*sizeof(float));
  (void)ws_size; (void)n_in; (void)out_size;

  k_init<<<64,256,0,stream>>>(W, W_bf, pcnt, NB);
  int PB = (E + 4*256 - 1) / (4*256);
  k_part<<<PB,256,0,stream>>>(row, col, pcnt, pbuf, E);
  k_scatter<<<NB,256,0,stream>>>(pcnt, pbuf, cnt, bucket, N);
  int GB = (N+63)/64;
  k_gemm<<<GB,256,0,stream>>>(x, W_bf, att, h_pair, s_i, s_j, N);
  k_agg<<<AGG_BLOCKS,256,0,stream>>>(h_pair, s_i, s_j, cnt, bucket, bias, out, gram_part, N);
  k_final<<<1,256,0,stream>>>(gram_part, AGG_BLOCKS, loss);
}

// Round 11
// 238.292 us; speedup vs baseline: 3.0845x; 3.0845x over previous
//
#include <hip/hip_runtime.h>
#include <math.h>

#define HC     128    // HEADS*OUT_CH
#define SLOT   64     // bucket row stride = max(in-deg+1); Poisson(16): P(>63) ~ 5e-19
#define AGG_BLOCKS 2048
#define NPART  8      // destination windows == XCD count
#define CHUNKS 256    // edge chunks for fill (grid = CHUNKS*NPART)

typedef unsigned int uint32;
typedef unsigned long long uint64;
typedef short bf16x8 __attribute__((ext_vector_type(8)));
typedef float f32x4 __attribute__((ext_vector_type(4)));
typedef int   i32x4 __attribute__((ext_vector_type(4)));

__device__ inline unsigned short f2bf(float f){
  uint32 u = __float_as_uint(f);
  u = (u + 0x7fffu + ((u >> 16) & 1u)) >> 16;
  return (unsigned short)u;
}
__device__ inline uint32 pack_bf2(float a, float b){
  return (uint32)f2bf(a) | ((uint32)f2bf(b) << 16);
}
// intra-wave LDS ordering (wave-private slices; no cross-wave barrier needed)
__device__ inline void lds_fence(){
  asm volatile("s_waitcnt lgkmcnt(0)" ::: "memory");
  __builtin_amdgcn_sched_barrier(0);
}

// ---------------- init: zero cnt + convert W to bf16 (once per call) ----------------

__global__ __launch_bounds__(256) void k_init(const float* __restrict__ W, unsigned short* __restrict__ W_bf,
                                              int* cnt, int N){
  int gid = blockIdx.x*256 + threadIdx.x;
  if (gid < 8192){                                 // 16384 W elems, 2 per thread
    float2 v = *(const float2*)&W[2*gid];
    *(uint32*)&W_bf[2*gid] = pack_bf2(v.x, v.y);
  }
  for (int i = gid; i < N; i += gridDim.x*256) cnt[i] = 0;
}

// ---------------- XCD-partitioned fixed-stride fill ----------------
// block b: scans edge chunk b/8 (4-wide vector loads), handles only dest window b%8
// (window -> one XCD's L2: bucket lines + per-node cursors stay local, full-line fills).
// bucket[d][pos] = src; cnt[d] = in-degree. Self-loop implicit in k_agg.

__global__ __launch_bounds__(256) void k_fill(const int* __restrict__ row, const int* __restrict__ col,
                                              int* cnt, int* bucket, int E, int N){
  int k = blockIdx.x & (NPART-1);
  int c = blockIdx.x >> 3;
  int per  = (((E + CHUNKS - 1) / CHUNKS) + 3) & ~3;   // 16B-aligned chunk base
  int base = c * per;
  int end  = base + per; if (end > E) end = E;
  int rng  = (N + NPART - 1) / NPART;
  int lo = k * rng, hi = lo + rng;
  int t = threadIdx.x;
  for (int i = base + t*4; i < end; i += 256*4){
    if (i + 4 <= end){
      i32x4 r4 = __builtin_nontemporal_load((const i32x4*)&row[i]);
      i32x4 c4 = __builtin_nontemporal_load((const i32x4*)&col[i]);
      #pragma unroll
      for (int q = 0; q < 4; ++q){
        int d = r4[q];
        if (d >= lo && d < hi){
          int pos = atomicAdd(&cnt[d], 1);
          if (pos < SLOT-1) bucket[(size_t)d*SLOT + pos] = c4[q];
        }
      }
    } else {
      for (int j = i; j < end; ++j){
        int d = row[j];
        if (d >= lo && d < hi){
          int pos = atomicAdd(&cnt[d], 1);
          if (pos < SLOT-1) bucket[(size_t)d*SLOT + pos] = col[j];
        }
      }
    }
  }
}

// ---------------- zero-LDS MFMA GEMM (bf16): W_bf from global (L1-hot), x NT ----------------
// 64-node tile, 4 waves x 16 rows. h_pair[n][hd*16+o] packs channels (32hd+o, 32hd+16+o).

__global__ __launch_bounds__(256) void k_gemm(const float* __restrict__ x, const unsigned short* __restrict__ W_bf,
                                              const float* __restrict__ att,
                                              uint32* __restrict__ h_pair,
                                              float* __restrict__ s_i, float* __restrict__ s_j, int N){
  int t = threadIdx.x;
  int w = t >> 6, l = t & 63;
  int o = l & 15, lg = l >> 4;
  int n0 = blockIdx.x * 64;

  int arow = n0 + w*16 + o;
  bool rok = (arow < N);
  const float* xr = x + (size_t)arow*128;
  bf16x8 afr[4];
  #pragma unroll
  for (int ks = 0; ks < 4; ++ks){
    f32x4 a0 = (f32x4){0.f,0.f,0.f,0.f}, a1 = a0;
    if (rok){
      a0 = __builtin_nontemporal_load((const f32x4*)&xr[ks*32 + lg*8]);
      a1 = __builtin_nontemporal_load((const f32x4*)&xr[ks*32 + lg*8 + 4]);
    }
    bf16x8 pa;
    pa[0]=(short)f2bf(a0[0]); pa[1]=(short)f2bf(a0[1]); pa[2]=(short)f2bf(a0[2]); pa[3]=(short)f2bf(a0[3]);
    pa[4]=(short)f2bf(a1[0]); pa[5]=(short)f2bf(a1[1]); pa[6]=(short)f2bf(a1[2]); pa[7]=(short)f2bf(a1[3]);
    afr[ks] = pa;
  }

  f32x4 acc[8];
  #pragma unroll
  for (int cf = 0; cf < 8; ++cf) acc[cf] = (f32x4){0.f,0.f,0.f,0.f};

  #pragma unroll
  for (int ks = 0; ks < 4; ++ks){
    #pragma unroll
    for (int cf = 0; cf < 8; ++cf){
      int rb = cf*16 + o;
      bf16x8 bfr = *(const bf16x8*)&W_bf[(size_t)rb*128 + ks*32 + lg*8];
      acc[cf] = __builtin_amdgcn_mfma_f32_16x16x32_bf16(afr[ks], bfr, acc[cf], 0, 0, 0);
    }
  }

  float ai0[4], ai1[4], aj0[4], aj1[4];
  #pragma unroll
  for (int hd = 0; hd < 4; ++hd){
    ai0[hd] = att[hd*64 + o];
    ai1[hd] = att[hd*64 + 16 + o];
    aj0[hd] = att[hd*64 + 32 + o];
    aj1[hd] = att[hd*64 + 48 + o];
  }

  // epilogue: D row = w*16 + lg*4 + q, col = cf*16 + o
  #pragma unroll
  for (int q = 0; q < 4; ++q){
    int node = n0 + w*16 + lg*4 + q;
    float v[8];
    #pragma unroll
    for (int cf = 0; cf < 8; ++cf) v[cf] = acc[cf][q];
    float pi[4], pj[4];
    #pragma unroll
    for (int hd = 0; hd < 4; ++hd){
      pi[hd] = v[2*hd]*ai0[hd] + v[2*hd+1]*ai1[hd];
      pj[hd] = v[2*hd]*aj0[hd] + v[2*hd+1]*aj1[hd];
    }
    #pragma unroll
    for (int sh = 1; sh < 16; sh <<= 1){
      #pragma unroll
      for (int hd = 0; hd < 4; ++hd){
        pi[hd] += __shfl_xor(pi[hd], sh);
        pj[hd] += __shfl_xor(pj[hd], sh);
      }
    }
    if (node < N){
      #pragma unroll
      for (int hd = 0; hd < 4; ++hd)
        __builtin_nontemporal_store(pack_bf2(v[2*hd], v[2*hd+1]),
                                    &h_pair[(size_t)node*64 + hd*16 + o]);
      if (o == 0){
        f32x4 vi = (f32x4){pi[0], pi[1], pi[2], pi[3]};
        f32x4 vj = (f32x4){pj[0], pj[1], pj[2], pj[3]};
        __builtin_nontemporal_store(vi, (f32x4*)&s_i[(size_t)node*4]);
        __builtin_nontemporal_store(vj, (f32x4*)&s_j[(size_t)node*4]);
      }
    }
  }
}

// ---------------- fused softmax + gram + weighted aggregation (independent wave per node) ----------------
// softmax mapping: lane l -> head g=l>>4, slot o=l&15 (wave-private LDS, intra-wave fences only).
// gather mapping:  half=l>>5, lw=l&31: lane loads uint2 of edge 2i+half; halves merged by shfl_xor(32).

__global__ __launch_bounds__(256) void k_agg(const uint32* __restrict__ h_pair, const float* __restrict__ s_i,
                                             const float* __restrict__ s_j, const int* __restrict__ cnt,
                                             const int* __restrict__ bucket,
                                             const float* __restrict__ bias, float* __restrict__ out,
                                             float* __restrict__ gram_part, int N){
  __shared__ __align__(16) float al[4][SLOT*4];   // per-wave alpha[j][head]
  __shared__ int   cs[4][SLOT];                   // per-wave src*32 (uint2 row offset)
  __shared__ float red[4][10];
  const uint2* hp2 = (const uint2*)h_pair;
  int t = threadIdx.x;
  int w = t >> 6, l = t & 63;
  int g = l >> 4, o = l & 15;        // softmax mapping
  int lw = l & 31, half = l >> 5;    // gather mapping
  int g2 = lw >> 3;
  int o0 = (2*lw) & 15;
  int cbase = 32*g2 + (half << 4) + o0;
  float2 bv = *(const float2*)&bias[cbase];
  float ga[10];
  #pragma unroll
  for (int p = 0; p < 10; ++p) ga[p] = 0.f;
  int TW = gridDim.x * 4;

  for (int n = blockIdx.x*4 + w; n < N; n += TW){
    int dc = cnt[n]; if (dc > SLOT-1) dc = SLOT-1;
    int d  = dc + 1;                               // + self loop (implicit, last slot)
    float4 si = *(const float4*)&s_i[(size_t)n*4];
    if (l < d){
      int src = (l < dc) ? __builtin_nontemporal_load(&bucket[(size_t)n*SLOT + l]) : n;
      cs[w][l] = src << 5;                         // uint2 row offset
      float4 sj = *(const float4*)&s_j[(size_t)src*4];
      float4 e;
      e.x = si.x + sj.x; e.y = si.y + sj.y; e.z = si.z + sj.z; e.w = si.w + sj.w;
      e.x = e.x >= 0.f ? e.x : 0.2f*e.x;
      e.y = e.y >= 0.f ? e.y : 0.2f*e.y;
      e.z = e.z >= 0.f ? e.z : 0.2f*e.z;
      e.w = e.w >= 0.f ? e.w : 0.2f*e.w;
      *(float4*)&al[w][l*4] = e;
    }
    if ((d & 1) && l == d){                        // pad edge for odd d: alpha 0, valid addr
      cs[w][l] = n << 5;
      *(float4*)&al[w][l*4] = make_float4(0.f,0.f,0.f,0.f);
    }
    lds_fence();
    float m = -3.4e38f;
    for (int j = o; j < d; j += 16) m = fmaxf(m, al[w][j*4 + g]);
    #pragma unroll
    for (int sh = 1; sh < 16; sh <<= 1) m = fmaxf(m, __shfl_xor(m, sh));
    float sum = 0.f;
    for (int j = o; j < d; j += 16){
      float v = __expf(al[w][j*4 + g] - m);
      al[w][j*4 + g] = v;
      sum += v;
    }
    #pragma unroll
    for (int sh = 1; sh < 16; sh <<= 1) sum += __shfl_xor(sum, sh);
    float r = 1.f/(sum + 1e-16f);
    for (int j = o; j < d; j += 16) al[w][j*4 + g] *= r;
    lds_fence();
    if (l < d){
      float4 a = *(const float4*)&al[w][l*4];
      ga[0] += a.x*a.x; ga[1] += a.x*a.y; ga[2] += a.x*a.z; ga[3] += a.x*a.w;
      ga[4] += a.y*a.y; ga[5] += a.y*a.z; ga[6] += a.y*a.w;
      ga[7] += a.z*a.z; ga[8] += a.z*a.w;
      ga[9] += a.w*a.w;
    }
    // half-wave gather: two edges per iteration across the wave, 4-deep unroll
    float a0 = 0.f, a1 = 0.f, a2 = 0.f, a3 = 0.f;
    const float* alw = &al[w][0];
    const int*   csw = &cs[w][0];
    int npair = (d + 1) >> 1;
    int i = 0;
    for (; i + 4 <= npair; i += 4){
      int e0 = 2*i + half, e1 = e0 + 2, e2 = e0 + 4, e3 = e0 + 6;
      int s0 = csw[e0], s1 = csw[e1], s2 = csw[e2], s3 = csw[e3];
      float w0 = alw[e0*4 + g2], w1 = alw[e1*4 + g2];
      float w2 = alw[e2*4 + g2], w3 = alw[e3*4 + g2];
      uint2 v0 = hp2[(size_t)(uint32)(s0 + lw)];
      uint2 v1 = hp2[(size_t)(uint32)(s1 + lw)];
      uint2 v2 = hp2[(size_t)(uint32)(s2 + lw)];
      uint2 v3 = hp2[(size_t)(uint32)(s3 + lw)];
      a0 += w0 * __uint_as_float(v0.x << 16);  a1 += w0 * __uint_as_float(v0.x & 0xffff0000u);
      a2 += w0 * __uint_as_float(v0.y << 16);  a3 += w0 * __uint_as_float(v0.y & 0xffff0000u);
      a0 += w1 * __uint_as_float(v1.x << 16);  a1 += w1 * __uint_as_float(v1.x & 0xffff0000u);
      a2 += w1 * __uint_as_float(v1.y << 16);  a3 += w1 * __uint_as_float(v1.y & 0xffff0000u);
      a0 += w2 * __uint_as_float(v2.x << 16);  a1 += w2 * __uint_as_float(v2.x & 0xffff0000u);
      a2 += w2 * __uint_as_float(v2.y << 16);  a3 += w2 * __uint_as_float(v2.y & 0xffff0000u);
      a0 += w3 * __uint_as_float(v3.x << 16);  a1 += w3 * __uint_as_float(v3.x & 0xffff0000u);
      a2 += w3 * __uint_as_float(v3.y << 16);  a3 += w3 * __uint_as_float(v3.y & 0xffff0000u);
    }
    for (; i < npair; ++i){
      int e = 2*i + half;
      float aw = alw[e*4 + g2];
      uint2 v = hp2[(size_t)(uint32)(csw[e] + lw)];
      a0 += aw * __uint_as_float(v.x << 16);  a1 += aw * __uint_as_float(v.x & 0xffff0000u);
      a2 += aw * __uint_as_float(v.y << 16);  a3 += aw * __uint_as_float(v.y & 0xffff0000u);
    }
    a0 += __shfl_xor(a0, 32);
    a1 += __shfl_xor(a1, 32);
    a2 += __shfl_xor(a2, 32);
    a3 += __shfl_xor(a3, 32);
    union { float f[2]; uint64 u; } st;
    st.f[0] = (half ? a1 : a0) + bv.x;
    st.f[1] = (half ? a3 : a2) + bv.y;
    __builtin_nontemporal_store(st.u, (uint64*)&out[(size_t)n*128 + cbase]);
    lds_fence();                                   // WAR guard before next staging write
  }
  __syncthreads();
  #pragma unroll
  for (int p = 0; p < 10; ++p){
    float v = ga[p];
    #pragma unroll
    for (int sh = 1; sh < 64; sh <<= 1) v += __shfl_xor(v, sh);
    ga[p] = v;
  }
  if (l == 0){
    #pragma unroll
    for (int p = 0; p < 10; ++p) red[w][p] = ga[p];
  }
  __syncthreads();
  if (t == 0){
    #pragma unroll
    for (int p = 0; p < 10; ++p)
      gram_part[(size_t)blockIdx.x*10 + p] = red[0][p] + red[1][p] + red[2][p] + red[3][p];
  }
}

// ---------------- gram reduce + diversity loss ----------------

__global__ __launch_bounds__(256) void k_final(const float* __restrict__ gram_part, int nparts,
                                               float* __restrict__ loss){
  __shared__ float red[4][10];
  int t = threadIdx.x;
  float acc[10];
  #pragma unroll
  for (int p = 0; p < 10; ++p) acc[p] = 0.f;
  for (int i = t; i < nparts; i += 256){
    #pragma unroll
    for (int p = 0; p < 10; ++p) acc[p] += gram_part[(size_t)i*10 + p];
  }
  #pragma unroll
  for (int p = 0; p < 10; ++p){
    float v = acc[p];
    #pragma unroll
    for (int sh = 1; sh < 64; sh <<= 1) v += __shfl_xor(v, sh);
    acc[p] = v;
  }
  if ((t & 63) == 0){
    #pragma unroll
    for (int p = 0; p < 10; ++p) red[t >> 6][p] = acc[p];
  }
  __syncthreads();
  if (t == 0){
    float gs[10];
    #pragma unroll
    for (int p = 0; p < 10; ++p) gs[p] = red[0][p] + red[1][p] + red[2][p] + red[3][p];
    float G[4][4];
    G[0][0]=gs[0]; G[0][1]=gs[1]; G[0][2]=gs[2]; G[0][3]=gs[3];
    G[1][0]=gs[1]; G[1][1]=gs[4]; G[1][2]=gs[5]; G[1][3]=gs[6];
    G[2][0]=gs[2]; G[2][1]=gs[5]; G[2][2]=gs[7]; G[2][3]=gs[8];
    G[3][0]=gs[3]; G[3][1]=gs[6]; G[3][2]=gs[8]; G[3][3]=gs[9];
    float nr[4];
    for (int i = 0; i < 4; ++i) nr[i] = sqrtf(G[i][i]);
    float ssum = 0.f;
    for (int i = 0; i < 4; ++i)
      for (int j = 0; j < 4; ++j)
        if (i != j) ssum += G[i][j] / fmaxf(nr[i]*nr[j], 1e-8f);
    loss[0] = ssum * (0.1f/16.f);
  }
}

// ---------------- launch ----------------

extern "C" void kernel_launch(void* const* d_in, const int* in_sizes, int n_in,
                              void* d_out, int out_size, void* d_ws, size_t ws_size,
                              hipStream_t stream){
  const float* x    = (const float*)d_in[0];
  const int*   edge = (const int*)d_in[1];
  const float* W    = (const float*)d_in[2];
  const float* att  = (const float*)d_in[3];
  const float* bias = (const float*)d_in[4];
  int N = in_sizes[0] / 128;
  int E = in_sizes[1] / 2;
  const int* row = edge;       // destinations
  const int* col = edge + E;   // sources
  float* out  = (float*)d_out;
  float* loss = out + (size_t)N*HC;

  char* wsb = (char*)d_ws;
  size_t off = 0;
  auto alloc = [&](size_t bytes)->void*{
    size_t o = (off + 255) & ~(size_t)255;
    off = o + bytes;
    return (void*)(wsb + o);
  };
  uint32* h_pair   = (uint32*)alloc((size_t)N*64*sizeof(uint32));
  float* s_i       = (float*)alloc((size_t)N*4*sizeof(float));
  float* s_j       = (float*)alloc((size_t)N*4*sizeof(float));
  int*   cnt       = (int*)alloc((size_t)N*sizeof(int));
  int*   bucket    = (int*)alloc((size_t)N*SLOT*sizeof(int));
  unsigned short* W_bf = (unsigned short*)alloc(16384*sizeof(unsigned short));
  float* gram_part = (float*)alloc((size_t)AGG_BLOCKS*10*sizeof(float));
  (void)ws_size; (void)n_in; (void)out_size;

  k_init<<<128,256,0,stream>>>(W, W_bf, cnt, N);
  k_fill<<<CHUNKS*NPART,256,0,stream>>>(row, col, cnt, bucket, E, N);
  int GB = (N+63)/64;
  k_gemm<<<GB,256,0,stream>>>(x, W_bf, att, h_pair, s_i, s_j, N);
  k_agg<<<AGG_BLOCKS,256,0,stream>>>(h_pair, s_i, s_j, cnt, bucket, bias, out, gram_part, N);
  k_final<<<1,256,0,stream>>>(gram_part, AGG_BLOCKS, loss);
}

// Round 12
// 231.708 us; speedup vs baseline: 3.1721x; 1.0284x over previous
//
#include <hip/hip_runtime.h>
#include <math.h>

#define HC     128    // HEADS*OUT_CH
#define SLOT   64     // bucket row stride = max(in-deg+1); Poisson(16): P(>63) ~ 5e-19
#define AGG_BLOCKS 2048
#define NPART  8      // destination windows == XCD count
#define CHUNKS 256    // edge chunks for fill (grid = CHUNKS*NPART)

typedef unsigned int uint32;
typedef unsigned long long uint64;
typedef short bf16x8 __attribute__((ext_vector_type(8)));
typedef float f32x4 __attribute__((ext_vector_type(4)));

__device__ inline unsigned short f2bf(float f){
  uint32 u = __float_as_uint(f);
  u = (u + 0x7fffu + ((u >> 16) & 1u)) >> 16;
  return (unsigned short)u;
}
__device__ inline uint32 pack_bf2(float a, float b){
  return (uint32)f2bf(a) | ((uint32)f2bf(b) << 16);
}
// intra-wave LDS ordering (wave-private slices; no cross-wave barrier needed)
__device__ inline void lds_fence(){
  asm volatile("s_waitcnt lgkmcnt(0)" ::: "memory");
  __builtin_amdgcn_sched_barrier(0);
}

// ---------------- init: zero cnt + convert W to bf16 ----------------

__global__ __launch_bounds__(256) void k_init(const float* __restrict__ W, unsigned short* __restrict__ W_bf,
                                              int* cnt, int N){
  int gid = blockIdx.x*256 + threadIdx.x;
  if (gid < 8192){                                 // 16384 W elems, 2 per thread
    float2 v = *(const float2*)&W[2*gid];
    *(uint32*)&W_bf[2*gid] = pack_bf2(v.x, v.y);
  }
  for (int i = gid; i < N; i += gridDim.x*256) cnt[i] = 0;
}

// ---------------- XCD-partitioned fixed-stride fill (round-6 proven version) ----------------
// block b: scans edge chunk b/8, handles only dest window b%8 (window -> one XCD's L2).
// bucket[d][pos] = src; cnt[d] = in-degree. Self-loop implicit in k_agg.

__global__ __launch_bounds__(256) void k_fill(const int* __restrict__ row, const int* __restrict__ col,
                                              int* cnt, int* bucket, int E, int N){
  int k = blockIdx.x & (NPART-1);
  int c = blockIdx.x >> 3;
  int per  = (E + CHUNKS - 1) / CHUNKS;
  int base = c * per;
  int end  = base + per; if (end > E) end = E;
  int rng  = (N + NPART - 1) / NPART;
  int lo = k * rng, hi = lo + rng;
  for (int i = base + threadIdx.x; i < end; i += 256){
    int d = row[i];
    if (d >= lo && d < hi){
      int pos = atomicAdd(&cnt[d], 1);
      if (pos < SLOT-1) bucket[(size_t)d*SLOT + pos] = col[i];
    }
  }
}

// ---------------- zero-LDS MFMA GEMM (bf16): W_bf from global (L1-hot), PLAIN h stores ----------------
// 64-node tile, 4 waves x 16 rows. h_pair[n][hd*16+o] packs channels (32hd+o, 32hd+16+o).
// h_pair/s_i/s_j stay L2-warm for k_agg (NT only on x: read-once input).

__global__ __launch_bounds__(256) void k_gemm(const float* __restrict__ x, const unsigned short* __restrict__ W_bf,
                                              const float* __restrict__ att,
                                              uint32* __restrict__ h_pair,
                                              float* __restrict__ s_i, float* __restrict__ s_j, int N){
  int t = threadIdx.x;
  int w = t >> 6, l = t & 63;
  int o = l & 15, lg = l >> 4;
  int n0 = blockIdx.x * 64;

  int arow = n0 + w*16 + o;
  bool rok = (arow < N);
  const float* xr = x + (size_t)arow*128;
  bf16x8 afr[4];
  #pragma unroll
  for (int ks = 0; ks < 4; ++ks){
    f32x4 a0 = (f32x4){0.f,0.f,0.f,0.f}, a1 = a0;
    if (rok){
      a0 = __builtin_nontemporal_load((const f32x4*)&xr[ks*32 + lg*8]);
      a1 = __builtin_nontemporal_load((const f32x4*)&xr[ks*32 + lg*8 + 4]);
    }
    bf16x8 pa;
    pa[0]=(short)f2bf(a0[0]); pa[1]=(short)f2bf(a0[1]); pa[2]=(short)f2bf(a0[2]); pa[3]=(short)f2bf(a0[3]);
    pa[4]=(short)f2bf(a1[0]); pa[5]=(short)f2bf(a1[1]); pa[6]=(short)f2bf(a1[2]); pa[7]=(short)f2bf(a1[3]);
    afr[ks] = pa;
  }

  f32x4 acc[8];
  #pragma unroll
  for (int cf = 0; cf < 8; ++cf) acc[cf] = (f32x4){0.f,0.f,0.f,0.f};

  #pragma unroll
  for (int ks = 0; ks < 4; ++ks){
    #pragma unroll
    for (int cf = 0; cf < 8; ++cf){
      int rb = cf*16 + o;
      bf16x8 bfr = *(const bf16x8*)&W_bf[(size_t)rb*128 + ks*32 + lg*8];
      acc[cf] = __builtin_amdgcn_mfma_f32_16x16x32_bf16(afr[ks], bfr, acc[cf], 0, 0, 0);
    }
  }

  float ai0[4], ai1[4], aj0[4], aj1[4];
  #pragma unroll
  for (int hd = 0; hd < 4; ++hd){
    ai0[hd] = att[hd*64 + o];
    ai1[hd] = att[hd*64 + 16 + o];
    aj0[hd] = att[hd*64 + 32 + o];
    aj1[hd] = att[hd*64 + 48 + o];
  }

  // epilogue: D row = w*16 + lg*4 + q, col = cf*16 + o
  #pragma unroll
  for (int q = 0; q < 4; ++q){
    int node = n0 + w*16 + lg*4 + q;
    float v[8];
    #pragma unroll
    for (int cf = 0; cf < 8; ++cf) v[cf] = acc[cf][q];
    float pi[4], pj[4];
    #pragma unroll
    for (int hd = 0; hd < 4; ++hd){
      pi[hd] = v[2*hd]*ai0[hd] + v[2*hd+1]*ai1[hd];
      pj[hd] = v[2*hd]*aj0[hd] + v[2*hd+1]*aj1[hd];
    }
    #pragma unroll
    for (int sh = 1; sh < 16; sh <<= 1){
      #pragma unroll
      for (int hd = 0; hd < 4; ++hd){
        pi[hd] += __shfl_xor(pi[hd], sh);
        pj[hd] += __shfl_xor(pj[hd], sh);
      }
    }
    if (node < N){
      #pragma unroll
      for (int hd = 0; hd < 4; ++hd)
        h_pair[(size_t)node*64 + hd*16 + o] = pack_bf2(v[2*hd], v[2*hd+1]);
      if (o == 0){
        *(float4*)&s_i[(size_t)node*4] = make_float4(pi[0], pi[1], pi[2], pi[3]);
        *(float4*)&s_j[(size_t)node*4] = make_float4(pj[0], pj[1], pj[2], pj[3]);
      }
    }
  }
}

// ---------------- fused softmax + gram + weighted aggregation (independent wave per node) ----------------
// softmax mapping: lane l -> head g=l>>4, slot o=l&15 (wave-private LDS, intra-wave fences only).
// gather mapping:  half=l>>5, lw=l&31: lane loads uint2 of edge 2i+half; halves merged by shfl_xor(32).
// PLAIN bucket/h_pair loads (L2-warm); NT only on the out store (write-once).

__global__ __launch_bounds__(256) void k_agg(const uint32* __restrict__ h_pair, const float* __restrict__ s_i,
                                             const float* __restrict__ s_j, const int* __restrict__ cnt,
                                             const int* __restrict__ bucket,
                                             const float* __restrict__ bias, float* __restrict__ out,
                                             float* __restrict__ gram_part, int N){
  __shared__ __align__(16) float al[4][SLOT*4];   // per-wave alpha[j][head]
  __shared__ int   cs[4][SLOT];                   // per-wave src*32 (uint2 row offset)
  __shared__ float red[4][10];
  const uint2* hp2 = (const uint2*)h_pair;
  int t = threadIdx.x;
  int w = t >> 6, l = t & 63;
  int g = l >> 4, o = l & 15;        // softmax mapping
  int lw = l & 31, half = l >> 5;    // gather mapping
  int g2 = lw >> 3;
  int o0 = (2*lw) & 15;
  int cbase = 32*g2 + (half << 4) + o0;
  float2 bv = *(const float2*)&bias[cbase];
  float ga[10];
  #pragma unroll
  for (int p = 0; p < 10; ++p) ga[p] = 0.f;
  int TW = gridDim.x * 4;

  for (int n = blockIdx.x*4 + w; n < N; n += TW){
    int dc = cnt[n]; if (dc > SLOT-1) dc = SLOT-1;
    int d  = dc + 1;                               // + self loop (implicit, last slot)
    float4 si = *(const float4*)&s_i[(size_t)n*4];
    if (l < d){
      int src = (l < dc) ? bucket[(size_t)n*SLOT + l] : n;
      cs[w][l] = src << 5;                         // uint2 row offset
      float4 sj = *(const float4*)&s_j[(size_t)src*4];
      float4 e;
      e.x = si.x + sj.x; e.y = si.y + sj.y; e.z = si.z + sj.z; e.w = si.w + sj.w;
      e.x = e.x >= 0.f ? e.x : 0.2f*e.x;
      e.y = e.y >= 0.f ? e.y : 0.2f*e.y;
      e.z = e.z >= 0.f ? e.z : 0.2f*e.z;
      e.w = e.w >= 0.f ? e.w : 0.2f*e.w;
      *(float4*)&al[w][l*4] = e;
    }
    if ((d & 1) && l == d){                        // pad edge for odd d: alpha 0, valid addr
      cs[w][l] = n << 5;
      *(float4*)&al[w][l*4] = make_float4(0.f,0.f,0.f,0.f);
    }
    lds_fence();
    float m = -3.4e38f;
    for (int j = o; j < d; j += 16) m = fmaxf(m, al[w][j*4 + g]);
    #pragma unroll
    for (int sh = 1; sh < 16; sh <<= 1) m = fmaxf(m, __shfl_xor(m, sh));
    float sum = 0.f;
    for (int j = o; j < d; j += 16){
      float v = __expf(al[w][j*4 + g] - m);
      al[w][j*4 + g] = v;
      sum += v;
    }
    #pragma unroll
    for (int sh = 1; sh < 16; sh <<= 1) sum += __shfl_xor(sum, sh);
    float r = 1.f/(sum + 1e-16f);
    for (int j = o; j < d; j += 16) al[w][j*4 + g] *= r;
    lds_fence();
    if (l < d){
      float4 a = *(const float4*)&al[w][l*4];
      ga[0] += a.x*a.x; ga[1] += a.x*a.y; ga[2] += a.x*a.z; ga[3] += a.x*a.w;
      ga[4] += a.y*a.y; ga[5] += a.y*a.z; ga[6] += a.y*a.w;
      ga[7] += a.z*a.z; ga[8] += a.z*a.w;
      ga[9] += a.w*a.w;
    }
    // half-wave gather: two edges per iteration across the wave, 4-deep unroll
    float a0 = 0.f, a1 = 0.f, a2 = 0.f, a3 = 0.f;
    const float* alw = &al[w][0];
    const int*   csw = &cs[w][0];
    int npair = (d + 1) >> 1;
    int i = 0;
    for (; i + 4 <= npair; i += 4){
      int e0 = 2*i + half, e1 = e0 + 2, e2 = e0 + 4, e3 = e0 + 6;
      int s0 = csw[e0], s1 = csw[e1], s2 = csw[e2], s3 = csw[e3];
      float w0 = alw[e0*4 + g2], w1 = alw[e1*4 + g2];
      float w2 = alw[e2*4 + g2], w3 = alw[e3*4 + g2];
      uint2 v0 = hp2[(size_t)(uint32)(s0 + lw)];
      uint2 v1 = hp2[(size_t)(uint32)(s1 + lw)];
      uint2 v2 = hp2[(size_t)(uint32)(s2 + lw)];
      uint2 v3 = hp2[(size_t)(uint32)(s3 + lw)];
      a0 += w0 * __uint_as_float(v0.x << 16);  a1 += w0 * __uint_as_float(v0.x & 0xffff0000u);
      a2 += w0 * __uint_as_float(v0.y << 16);  a3 += w0 * __uint_as_float(v0.y & 0xffff0000u);
      a0 += w1 * __uint_as_float(v1.x << 16);  a1 += w1 * __uint_as_float(v1.x & 0xffff0000u);
      a2 += w1 * __uint_as_float(v1.y << 16);  a3 += w1 * __uint_as_float(v1.y & 0xffff0000u);
      a0 += w2 * __uint_as_float(v2.x << 16);  a1 += w2 * __uint_as_float(v2.x & 0xffff0000u);
      a2 += w2 * __uint_as_float(v2.y << 16);  a3 += w2 * __uint_as_float(v2.y & 0xffff0000u);
      a0 += w3 * __uint_as_float(v3.x << 16);  a1 += w3 * __uint_as_float(v3.x & 0xffff0000u);
      a2 += w3 * __uint_as_float(v3.y << 16);  a3 += w3 * __uint_as_float(v3.y & 0xffff0000u);
    }
    for (; i < npair; ++i){
      int e = 2*i + half;
      float aw = alw[e*4 + g2];
      uint2 v = hp2[(size_t)(uint32)(csw[e] + lw)];
      a0 += aw * __uint_as_float(v.x << 16);  a1 += aw * __uint_as_float(v.x & 0xffff0000u);
      a2 += aw * __uint_as_float(v.y << 16);  a3 += aw * __uint_as_float(v.y & 0xffff0000u);
    }
    a0 += __shfl_xor(a0, 32);
    a1 += __shfl_xor(a1, 32);
    a2 += __shfl_xor(a2, 32);
    a3 += __shfl_xor(a3, 32);
    union { float f[2]; uint64 u; } st;
    st.f[0] = (half ? a1 : a0) + bv.x;
    st.f[1] = (half ? a3 : a2) + bv.y;
    __builtin_nontemporal_store(st.u, (uint64*)&out[(size_t)n*128 + cbase]);
    lds_fence();                                   // WAR guard before next staging write
  }
  __syncthreads();
  #pragma unroll
  for (int p = 0; p < 10; ++p){
    float v = ga[p];
    #pragma unroll
    for (int sh = 1; sh < 64; sh <<= 1) v += __shfl_xor(v, sh);
    ga[p] = v;
  }
  if (l == 0){
    #pragma unroll
    for (int p = 0; p < 10; ++p) red[w][p] = ga[p];
  }
  __syncthreads();
  if (t == 0){
    #pragma unroll
    for (int p = 0; p < 10; ++p)
      gram_part[(size_t)blockIdx.x*10 + p] = red[0][p] + red[1][p] + red[2][p] + red[3][p];
  }
}

// ---------------- gram reduce + diversity loss ----------------

__global__ __launch_bounds__(256) void k_final(const float* __restrict__ gram_part, int nparts,
                                               float* __restrict__ loss){
  __shared__ float red[4][10];
  int t = threadIdx.x;
  float acc[10];
  #pragma unroll
  for (int p = 0; p < 10; ++p) acc[p] = 0.f;
  for (int i = t; i < nparts; i += 256){
    #pragma unroll
    for (int p = 0; p < 10; ++p) acc[p] += gram_part[(size_t)i*10 + p];
  }
  #pragma unroll
  for (int p = 0; p < 10; ++p){
    float v = acc[p];
    #pragma unroll
    for (int sh = 1; sh < 64; sh <<= 1) v += __shfl_xor(v, sh);
    acc[p] = v;
  }
  if ((t & 63) == 0){
    #pragma unroll
    for (int p = 0; p < 10; ++p) red[t >> 6][p] = acc[p];
  }
  __syncthreads();
  if (t == 0){
    float gs[10];
    #pragma unroll
    for (int p = 0; p < 10; ++p) gs[p] = red[0][p] + red[1][p] + red[2][p] + red[3][p];
    float G[4][4];
    G[0][0]=gs[0]; G[0][1]=gs[1]; G[0][2]=gs[2]; G[0][3]=gs[3];
    G[1][0]=gs[1]; G[1][1]=gs[4]; G[1][2]=gs[5]; G[1][3]=gs[6];
    G[2][0]=gs[2]; G[2][1]=gs[5]; G[2][2]=gs[7]; G[2][3]=gs[8];
    G[3][0]=gs[3]; G[3][1]=gs[6]; G[3][2]=gs[8]; G[3][3]=gs[9];
    float nr[4];
    for (int i = 0; i < 4; ++i) nr[i] = sqrtf(G[i][i]);
    float ssum = 0.f;
    for (int i = 0; i < 4; ++i)
      for (int j = 0; j < 4; ++j)
        if (i != j) ssum += G[i][j] / fmaxf(nr[i]*nr[j], 1e-8f);
    loss[0] = ssum * (0.1f/16.f);
  }
}

// ---------------- launch ----------------

extern "C" void kernel_launch(void* const* d_in, const int* in_sizes, int n_in,
                              void* d_out, int out_size, void* d_ws, size_t ws_size,
                              hipStream_t stream){
  const float* x    = (const float*)d_in[0];
  const int*   edge = (const int*)d_in[1];
  const float* W    = (const float*)d_in[2];
  const float* att  = (const float*)d_in[3];
  const float* bias = (const float*)d_in[4];
  int N = in_sizes[0] / 128;
  int E = in_sizes[1] / 2;
  const int* row = edge;       // destinations
  const int* col = edge + E;   // sources
  float* out  = (float*)d_out;
  float* loss = out + (size_t)N*HC;

  char* wsb = (char*)d_ws;
  size_t off = 0;
  auto alloc = [&](size_t bytes)->void*{
    size_t o = (off + 255) & ~(size_t)255;
    off = o + bytes;
    return (void*)(wsb + o);
  };
  uint32* h_pair   = (uint32*)alloc((size_t)N*64*sizeof(uint32));
  float* s_i       = (float*)alloc((size_t)N*4*sizeof(float));
  float* s_j       = (float*)alloc((size_t)N*4*sizeof(float));
  int*   cnt       = (int*)alloc((size_t)N*sizeof(int));
  int*   bucket    = (int*)alloc((size_t)N*SLOT*sizeof(int));
  unsigned short* W_bf = (unsigned short*)alloc(16384*sizeof(unsigned short));
  float* gram_part = (float*)alloc((size_t)AGG_BLOCKS*10*sizeof(float));
  (void)ws_size; (void)n_in; (void)out_size;

  k_init<<<128,256,0,stream>>>(W, W_bf, cnt, N);
  k_fill<<<CHUNKS*NPART,256,0,stream>>>(row, col, cnt, bucket, E, N);
  int GB = (N+63)/64;
  k_gemm<<<GB,256,0,stream>>>(x, W_bf, att, h_pair, s_i, s_j, N);
  k_agg<<<AGG_BLOCKS,256,0,stream>>>(h_pair, s_i, s_j, cnt, bucket, bias, out, gram_part, N);
  k_final<<<1,256,0,stream>>>(gram_part, AGG_BLOCKS, loss);
}

// Round 13
// 213.871 us; speedup vs baseline: 3.4367x; 1.0834x over previous
//
#include <hip/hip_runtime.h>
#include <math.h>

#define HC     128    // HEADS*OUT_CH
#define SLOT   64     // bucket row stride = max(in-deg+1); Poisson(16): P(>63) ~ 5e-19
#define AGG_BLOCKS 2048
#define NPART  8      // destination windows == XCD count
#define CHUNKS 256    // edge chunks for fill (grid = CHUNKS*NPART)

typedef unsigned int uint32;
typedef short bf16x8 __attribute__((ext_vector_type(8)));
typedef float f32x4 __attribute__((ext_vector_type(4)));

__device__ inline unsigned short f2bf(float f){
  uint32 u = __float_as_uint(f);
  u = (u + 0x7fffu + ((u >> 16) & 1u)) >> 16;
  return (unsigned short)u;
}
__device__ inline uint32 pack_bf2(float a, float b){
  return (uint32)f2bf(a) | ((uint32)f2bf(b) << 16);
}
// intra-wave LDS ordering (wave-private slices; no cross-wave barrier needed)
__device__ inline void lds_fence(){
  asm volatile("s_waitcnt lgkmcnt(0)" ::: "memory");
  __builtin_amdgcn_sched_barrier(0);
}

// ---------------- XCD-partitioned fixed-stride fill (round-6 proven) ----------------
// block b: scans edge chunk b/8, handles only dest window b%8 (window -> one XCD's L2).
// bucket[d][pos] = src; cnt[d] = in-degree. Self-loop is implicit (slot cnt[d] in k_agg).

__global__ __launch_bounds__(256) void k_fill(const int* __restrict__ row, const int* __restrict__ col,
                                              int* cnt, int* bucket, int E, int N){
  int k = blockIdx.x & (NPART-1);
  int c = blockIdx.x >> 3;
  int per  = (E + CHUNKS - 1) / CHUNKS;
  int base = c * per;
  int end  = base + per; if (end > E) end = E;
  int rng  = (N + NPART - 1) / NPART;
  int lo = k * rng, hi = lo + rng;
  for (int i = base + threadIdx.x; i < end; i += 256){
    int d = row[i];
    if (d >= lo && d < hi){
      int pos = atomicAdd(&cnt[d], 1);
      if (pos < SLOT-1) bucket[(size_t)d*SLOT + pos] = col[i];
    }
  }
}

// ---------------- MFMA GEMM (bf16): W in LDS, x direct-to-registers (round-6 proven) ----------------
// 64-node tile, 4 waves x 16 rows. h_pair[n][hd*16+o] packs channels (32hd+o, 32hd+16+o).

__global__ __launch_bounds__(256) void k_gemm(const float* __restrict__ x, const float* __restrict__ W,
                                              const float* __restrict__ att,
                                              uint32* __restrict__ h_pair,
                                              float* __restrict__ s_i, float* __restrict__ s_j, int N){
  __shared__ __align__(16) unsigned short Blds[128*128];  // W as bf16, [row][swz chunk], 32 KB
  int t = threadIdx.x;
  int w = t >> 6, l = t & 63;
  int o = l & 15, lg = l >> 4;
  int n0 = blockIdx.x * 64;

  // stage W into LDS
  #pragma unroll
  for (int i = 0; i < 8; ++i){
    int id = t + i*256;          // 0..2047
    int r  = id >> 4, ck = id & 15;
    int sw = ck ^ (r & 7);
    float4 b0 = *(const float4*)&W[(size_t)r*128 + ck*8];
    float4 b1 = *(const float4*)&W[(size_t)r*128 + ck*8 + 4];
    bf16x8 pb;
    pb[0]=(short)f2bf(b0.x); pb[1]=(short)f2bf(b0.y); pb[2]=(short)f2bf(b0.z); pb[3]=(short)f2bf(b0.w);
    pb[4]=(short)f2bf(b1.x); pb[5]=(short)f2bf(b1.y); pb[6]=(short)f2bf(b1.z); pb[7]=(short)f2bf(b1.w);
    *(bf16x8*)&Blds[r*128 + sw*8] = pb;
  }

  // A-fragments straight from global (rows block-exclusive; no LDS round-trip)
  int arow = n0 + w*16 + o;
  bool rok = (arow < N);
  const float* xr = x + (size_t)arow*128;
  bf16x8 afr[4];
  #pragma unroll
  for (int ks = 0; ks < 4; ++ks){
    float4 a0 = make_float4(0.f,0.f,0.f,0.f), a1 = a0;
    if (rok){
      a0 = *(const float4*)&xr[ks*32 + lg*8];
      a1 = *(const float4*)&xr[ks*32 + lg*8 + 4];
    }
    bf16x8 pa;
    pa[0]=(short)f2bf(a0.x); pa[1]=(short)f2bf(a0.y); pa[2]=(short)f2bf(a0.z); pa[3]=(short)f2bf(a0.w);
    pa[4]=(short)f2bf(a1.x); pa[5]=(short)f2bf(a1.y); pa[6]=(short)f2bf(a1.z); pa[7]=(short)f2bf(a1.w);
    afr[ks] = pa;
  }
  __syncthreads();

  f32x4 acc[8];
  #pragma unroll
  for (int cf = 0; cf < 8; ++cf) acc[cf] = (f32x4){0.f,0.f,0.f,0.f};

  #pragma unroll
  for (int ks = 0; ks < 4; ++ks){
    int ckk = ks*4 + lg;
    #pragma unroll
    for (int cf = 0; cf < 8; ++cf){
      int rb = cf*16 + o;
      bf16x8 bfr = *(const bf16x8*)&Blds[rb*128 + (ckk ^ (rb & 7))*8];
      acc[cf] = __builtin_amdgcn_mfma_f32_16x16x32_bf16(afr[ks], bfr, acc[cf], 0, 0, 0);
    }
  }

  // att weights for this lane's column o
  float ai0[4], ai1[4], aj0[4], aj1[4];
  #pragma unroll
  for (int hd = 0; hd < 4; ++hd){
    ai0[hd] = att[hd*64 + o];
    ai1[hd] = att[hd*64 + 16 + o];
    aj0[hd] = att[hd*64 + 32 + o];
    aj1[hd] = att[hd*64 + 48 + o];
  }

  // epilogue: D row = w*16 + lg*4 + q, col = cf*16 + o
  #pragma unroll
  for (int q = 0; q < 4; ++q){
    int node = n0 + w*16 + lg*4 + q;
    float v[8];
    #pragma unroll
    for (int cf = 0; cf < 8; ++cf) v[cf] = acc[cf][q];
    float pi[4], pj[4];
    #pragma unroll
    for (int hd = 0; hd < 4; ++hd){
      pi[hd] = v[2*hd]*ai0[hd] + v[2*hd+1]*ai1[hd];
      pj[hd] = v[2*hd]*aj0[hd] + v[2*hd+1]*aj1[hd];
    }
    #pragma unroll
    for (int sh = 1; sh < 16; sh <<= 1){
      #pragma unroll
      for (int hd = 0; hd < 4; ++hd){
        pi[hd] += __shfl_xor(pi[hd], sh);
        pj[hd] += __shfl_xor(pj[hd], sh);
      }
    }
    if (node < N){
      #pragma unroll
      for (int hd = 0; hd < 4; ++hd)
        h_pair[(size_t)node*64 + hd*16 + o] = pack_bf2(v[2*hd], v[2*hd+1]);
      if (o == 0){
        *(float4*)&s_i[(size_t)node*4] = make_float4(pi[0], pi[1], pi[2], pi[3]);
        *(float4*)&s_j[(size_t)node*4] = make_float4(pj[0], pj[1], pj[2], pj[3]);
      }
    }
  }
}

// ---------------- fused softmax + gram + weighted aggregation (independent wave per node) ----------------
// round-6 proven structure; ONLY change: gather loop 4-deep -> 8-deep unroll (more MLP).
// lane l: head g=l>>4, slot o=l&15; owns channels 32g+o and 32g+16+o (h_pair layout).

__global__ __launch_bounds__(256) void k_agg(const uint32* __restrict__ h_pair, const float* __restrict__ s_i,
                                             const float* __restrict__ s_j, const int* __restrict__ cnt,
                                             const int* __restrict__ bucket,
                                             const float* __restrict__ bias, float* __restrict__ out,
                                             float* __restrict__ gram_part, int N){
  __shared__ __align__(16) float al[4][SLOT*4];   // per-wave alpha[j][head]
  __shared__ int   cs[4][SLOT];                   // per-wave src*64 (pre-shifted)
  __shared__ float red[4][10];
  int t = threadIdx.x;
  int w = t >> 6, l = t & 63;
  int g = l >> 4, o = l & 15;
  float b0 = bias[32*g + o];
  float b1 = bias[32*g + 16 + o];
  float ga[10];
  #pragma unroll
  for (int p = 0; p < 10; ++p) ga[p] = 0.f;
  int TW = gridDim.x * 4;

  for (int n = blockIdx.x*4 + w; n < N; n += TW){
    int dc = cnt[n]; if (dc > SLOT-1) dc = SLOT-1;
    int d  = dc + 1;                               // + self loop (implicit, last slot)
    float4 si = *(const float4*)&s_i[(size_t)n*4];
    if (l < d){
      int src = (l < dc) ? bucket[(size_t)n*SLOT + l] : n;
      cs[w][l] = src << 6;                         // pre-multiplied h_pair row offset
      float4 sj = *(const float4*)&s_j[(size_t)src*4];
      float4 e;
      e.x = si.x + sj.x; e.y = si.y + sj.y; e.z = si.z + sj.z; e.w = si.w + sj.w;
      e.x = e.x >= 0.f ? e.x : 0.2f*e.x;
      e.y = e.y >= 0.f ? e.y : 0.2f*e.y;
      e.z = e.z >= 0.f ? e.z : 0.2f*e.z;
      e.w = e.w >= 0.f ? e.w : 0.2f*e.w;
      *(float4*)&al[w][l*4] = e;
    }
    lds_fence();
    // per-head softmax: 16 lanes per head, d <= 64 -> at most 4 strided slots
    float m = -3.4e38f;
    for (int j = o; j < d; j += 16) m = fmaxf(m, al[w][j*4 + g]);
    #pragma unroll
    for (int sh = 1; sh < 16; sh <<= 1) m = fmaxf(m, __shfl_xor(m, sh));
    float sum = 0.f;
    for (int j = o; j < d; j += 16){
      float v = __expf(al[w][j*4 + g] - m);
      al[w][j*4 + g] = v;
      sum += v;
    }
    #pragma unroll
    for (int sh = 1; sh < 16; sh <<= 1) sum += __shfl_xor(sum, sh);
    float r = 1.f/(sum + 1e-16f);
    for (int j = o; j < d; j += 16) al[w][j*4 + g] *= r;
    lds_fence();
    // gram partials (single shot: d <= 64)
    if (l < d){
      float4 a = *(const float4*)&al[w][l*4];
      ga[0] += a.x*a.x; ga[1] += a.x*a.y; ga[2] += a.x*a.z; ga[3] += a.x*a.w;
      ga[4] += a.y*a.y; ga[5] += a.y*a.z; ga[6] += a.y*a.w;
      ga[7] += a.z*a.z; ga[8] += a.z*a.w;
      ga[9] += a.w*a.w;
    }
    // weighted gather, 8-deep load batching (r6 was 4-deep; more MLP per wave)
    float a0 = 0.f, a1 = 0.f;
    const float* alw = &al[w][0];
    const int*   csw = &cs[w][0];
    int j = 0;
    for (; j + 8 <= d; j += 8){
      uint32 v[8]; float wt[8];
      #pragma unroll
      for (int q = 0; q < 8; ++q){
        wt[q] = alw[(j+q)*4 + g];
        v[q]  = h_pair[(size_t)(uint32)(csw[j+q] + l)];
      }
      #pragma unroll
      for (int q = 0; q < 8; ++q){
        a0 += wt[q] * __uint_as_float(v[q] << 16);
        a1 += wt[q] * __uint_as_float(v[q] & 0xffff0000u);
      }
    }
    for (; j + 4 <= d; j += 4){
      uint32 v[4]; float wt[4];
      #pragma unroll
      for (int q = 0; q < 4; ++q){
        wt[q] = alw[(j+q)*4 + g];
        v[q]  = h_pair[(size_t)(uint32)(csw[j+q] + l)];
      }
      #pragma unroll
      for (int q = 0; q < 4; ++q){
        a0 += wt[q] * __uint_as_float(v[q] << 16);
        a1 += wt[q] * __uint_as_float(v[q] & 0xffff0000u);
      }
    }
    for (; j < d; ++j){
      float aw = alw[j*4 + g];
      uint32 v = h_pair[(size_t)(uint32)(csw[j] + l)];
      a0 += aw * __uint_as_float(v << 16);
      a1 += aw * __uint_as_float(v & 0xffff0000u);
    }
    out[(size_t)n*128 + 32*g + o]      = a0 + b0;
    out[(size_t)n*128 + 32*g + 16 + o] = a1 + b1;
    lds_fence();                                   // WAR guard before next staging write
  }
  __syncthreads();
  #pragma unroll
  for (int p = 0; p < 10; ++p){
    float v = ga[p];
    #pragma unroll
    for (int sh = 1; sh < 64; sh <<= 1) v += __shfl_xor(v, sh);
    ga[p] = v;
  }
  if (l == 0){
    #pragma unroll
    for (int p = 0; p < 10; ++p) red[w][p] = ga[p];
  }
  __syncthreads();
  if (t == 0){
    #pragma unroll
    for (int p = 0; p < 10; ++p)
      gram_part[(size_t)blockIdx.x*10 + p] = red[0][p] + red[1][p] + red[2][p] + red[3][p];
  }
}

// ---------------- gram reduce + diversity loss ----------------

__global__ __launch_bounds__(256) void k_final(const float* __restrict__ gram_part, int nparts,
                                               float* __restrict__ loss){
  __shared__ float red[4][10];
  int t = threadIdx.x;
  float acc[10];
  #pragma unroll
  for (int p = 0; p < 10; ++p) acc[p] = 0.f;
  for (int i = t; i < nparts; i += 256){
    #pragma unroll
    for (int p = 0; p < 10; ++p) acc[p] += gram_part[(size_t)i*10 + p];
  }
  #pragma unroll
  for (int p = 0; p < 10; ++p){
    float v = acc[p];
    #pragma unroll
    for (int sh = 1; sh < 64; sh <<= 1) v += __shfl_xor(v, sh);
    acc[p] = v;
  }
  if ((t & 63) == 0){
    #pragma unroll
    for (int p = 0; p < 10; ++p) red[t >> 6][p] = acc[p];
  }
  __syncthreads();
  if (t == 0){
    float gs[10];
    #pragma unroll
    for (int p = 0; p < 10; ++p) gs[p] = red[0][p] + red[1][p] + red[2][p] + red[3][p];
    float G[4][4];
    G[0][0]=gs[0]; G[0][1]=gs[1]; G[0][2]=gs[2]; G[0][3]=gs[3];
    G[1][0]=gs[1]; G[1][1]=gs[4]; G[1][2]=gs[5]; G[1][3]=gs[6];
    G[2][0]=gs[2]; G[2][1]=gs[5]; G[2][2]=gs[7]; G[2][3]=gs[8];
    G[3][0]=gs[3]; G[3][1]=gs[6]; G[3][2]=gs[8]; G[3][3]=gs[9];
    float nr[4];
    for (int i = 0; i < 4; ++i) nr[i] = sqrtf(G[i][i]);
    float ssum = 0.f;
    for (int i = 0; i < 4; ++i)
      for (int j = 0; j < 4; ++j)
        if (i != j) ssum += G[i][j] / fmaxf(nr[i]*nr[j], 1e-8f);
    loss[0] = ssum * (0.1f/16.f);
  }
}

// ---------------- launch ----------------

extern "C" void kernel_launch(void* const* d_in, const int* in_sizes, int n_in,
                              void* d_out, int out_size, void* d_ws, size_t ws_size,
                              hipStream_t stream){
  const float* x    = (const float*)d_in[0];
  const int*   edge = (const int*)d_in[1];
  const float* W    = (const float*)d_in[2];
  const float* att  = (const float*)d_in[3];
  const float* bias = (const float*)d_in[4];
  int N = in_sizes[0] / 128;
  int E = in_sizes[1] / 2;
  const int* row = edge;       // destinations
  const int* col = edge + E;   // sources
  float* out  = (float*)d_out;
  float* loss = out + (size_t)N*HC;

  char* wsb = (char*)d_ws;
  size_t off = 0;
  auto alloc = [&](size_t bytes)->void*{
    size_t o = (off + 255) & ~(size_t)255;
    off = o + bytes;
    return (void*)(wsb + o);
  };
  uint32* h_pair   = (uint32*)alloc((size_t)N*64*sizeof(uint32));
  float* s_i       = (float*)alloc((size_t)N*4*sizeof(float));
  float* s_j       = (float*)alloc((size_t)N*4*sizeof(float));
  int*   cnt       = (int*)alloc((size_t)N*sizeof(int));
  int*   bucket    = (int*)alloc((size_t)N*SLOT*sizeof(int));
  float* gram_part = (float*)alloc((size_t)AGG_BLOCKS*10*sizeof(float));
  (void)ws_size; (void)n_in; (void)out_size;

  hipMemsetAsync(cnt, 0, (size_t)N*sizeof(int), stream);
  k_fill<<<CHUNKS*NPART,256,0,stream>>>(row, col, cnt, bucket, E, N);
  int GB = (N+63)/64;
  k_gemm<<<GB,256,0,stream>>>(x, W, att, h_pair, s_i, s_j, N);
  k_agg<<<AGG_BLOCKS,256,0,stream>>>(h_pair, s_i, s_j, cnt, bucket, bias, out, gram_part, N);
  k_final<<<1,256,0,stream>>>(gram_part, AGG_BLOCKS, loss);
}

// Round 14
// 192.900 us; speedup vs baseline: 3.8103x; 1.1087x over previous
//
#include <hip/hip_runtime.h>
#include <math.h>

#define HC     128    // HEADS*OUT_CH
#define SLOT   64     // bucket row stride = max(in-deg+1); Poisson(16): P(>63) ~ 5e-19
#define AGG_BLOCKS 2048
#define NPART  8      // destination windows == XCD count
#define CHUNKS 256    // edge chunks for fill (grid = CHUNKS*NPART)

typedef unsigned int uint32;
typedef short bf16x8 __attribute__((ext_vector_type(8)));
typedef float f32x4 __attribute__((ext_vector_type(4)));

__device__ inline unsigned short f2bf(float f){
  uint32 u = __float_as_uint(f);
  u = (u + 0x7fffu + ((u >> 16) & 1u)) >> 16;
  return (unsigned short)u;
}
__device__ inline uint32 pack_bf2(float a, float b){
  return (uint32)f2bf(a) | ((uint32)f2bf(b) << 16);
}
// intra-wave LDS ordering (wave-private slices; no cross-wave barrier needed)
__device__ inline void lds_fence(){
  asm volatile("s_waitcnt lgkmcnt(0)" ::: "memory");
  __builtin_amdgcn_sched_barrier(0);
}

// ---------------- XCD-partitioned fixed-stride fill, 4-edge atomic batching ----------------
// block b: scans edge chunk b/8, handles only dest window b%8 (window -> one XCD's L2).
// Phase-split per 4 edges: loads -> masks -> 4 atomics in flight -> stores.
// bucket[d][pos] = src; cnt[d] = in-degree. Self-loop is implicit (slot cnt[d] in k_agg).

__global__ __launch_bounds__(256) void k_fill(const int* __restrict__ row, const int* __restrict__ col,
                                              int* cnt, int* bucket, int E, int N){
  int k = blockIdx.x & (NPART-1);
  int c = blockIdx.x >> 3;
  int per  = (E + CHUNKS - 1) / CHUNKS;
  int base = c * per;
  int end  = base + per; if (end > E) end = E;
  int rng  = (N + NPART - 1) / NPART;
  int lo = k * rng, hi = lo + rng;
  int t = threadIdx.x;
  for (int i = base + t; i < end; i += 1024){
    int  dd[4], cc[4], pos[4];
    bool ok[4];
    #pragma unroll
    for (int q = 0; q < 4; ++q){
      int idx = i + q*256;
      bool inr = (idx < end);
      dd[q] = inr ? row[idx] : -1;
      cc[q] = inr ? col[idx] : 0;
      ok[q] = inr && (dd[q] >= lo) && (dd[q] < hi);
    }
    #pragma unroll
    for (int q = 0; q < 4; ++q)
      if (ok[q]) pos[q] = atomicAdd(&cnt[dd[q]], 1);
    #pragma unroll
    for (int q = 0; q < 4; ++q)
      if (ok[q] && pos[q] < SLOT-1) bucket[(size_t)dd[q]*SLOT + pos[q]] = cc[q];
  }
}

// ---------------- MFMA GEMM (bf16): W in LDS, x direct-to-registers (round-6 proven) ----------------
// 64-node tile, 4 waves x 16 rows. h_pair[n][hd*16+o] packs channels (32hd+o, 32hd+16+o).

__global__ __launch_bounds__(256) void k_gemm(const float* __restrict__ x, const float* __restrict__ W,
                                              const float* __restrict__ att,
                                              uint32* __restrict__ h_pair,
                                              float* __restrict__ s_i, float* __restrict__ s_j, int N){
  __shared__ __align__(16) unsigned short Blds[128*128];  // W as bf16, [row][swz chunk], 32 KB
  int t = threadIdx.x;
  int w = t >> 6, l = t & 63;
  int o = l & 15, lg = l >> 4;
  int n0 = blockIdx.x * 64;

  // stage W into LDS
  #pragma unroll
  for (int i = 0; i < 8; ++i){
    int id = t + i*256;          // 0..2047
    int r  = id >> 4, ck = id & 15;
    int sw = ck ^ (r & 7);
    float4 b0 = *(const float4*)&W[(size_t)r*128 + ck*8];
    float4 b1 = *(const float4*)&W[(size_t)r*128 + ck*8 + 4];
    bf16x8 pb;
    pb[0]=(short)f2bf(b0.x); pb[1]=(short)f2bf(b0.y); pb[2]=(short)f2bf(b0.z); pb[3]=(short)f2bf(b0.w);
    pb[4]=(short)f2bf(b1.x); pb[5]=(short)f2bf(b1.y); pb[6]=(short)f2bf(b1.z); pb[7]=(short)f2bf(b1.w);
    *(bf16x8*)&Blds[r*128 + sw*8] = pb;
  }

  // A-fragments straight from global (rows block-exclusive; no LDS round-trip)
  int arow = n0 + w*16 + o;
  bool rok = (arow < N);
  const float* xr = x + (size_t)arow*128;
  bf16x8 afr[4];
  #pragma unroll
  for (int ks = 0; ks < 4; ++ks){
    float4 a0 = make_float4(0.f,0.f,0.f,0.f), a1 = a0;
    if (rok){
      a0 = *(const float4*)&xr[ks*32 + lg*8];
      a1 = *(const float4*)&xr[ks*32 + lg*8 + 4];
    }
    bf16x8 pa;
    pa[0]=(short)f2bf(a0.x); pa[1]=(short)f2bf(a0.y); pa[2]=(short)f2bf(a0.z); pa[3]=(short)f2bf(a0.w);
    pa[4]=(short)f2bf(a1.x); pa[5]=(short)f2bf(a1.y); pa[6]=(short)f2bf(a1.z); pa[7]=(short)f2bf(a1.w);
    afr[ks] = pa;
  }
  __syncthreads();

  f32x4 acc[8];
  #pragma unroll
  for (int cf = 0; cf < 8; ++cf) acc[cf] = (f32x4){0.f,0.f,0.f,0.f};

  #pragma unroll
  for (int ks = 0; ks < 4; ++ks){
    int ckk = ks*4 + lg;
    #pragma unroll
    for (int cf = 0; cf < 8; ++cf){
      int rb = cf*16 + o;
      bf16x8 bfr = *(const bf16x8*)&Blds[rb*128 + (ckk ^ (rb & 7))*8];
      acc[cf] = __builtin_amdgcn_mfma_f32_16x16x32_bf16(afr[ks], bfr, acc[cf], 0, 0, 0);
    }
  }

  // att weights for this lane's column o
  float ai0[4], ai1[4], aj0[4], aj1[4];
  #pragma unroll
  for (int hd = 0; hd < 4; ++hd){
    ai0[hd] = att[hd*64 + o];
    ai1[hd] = att[hd*64 + 16 + o];
    aj0[hd] = att[hd*64 + 32 + o];
    aj1[hd] = att[hd*64 + 48 + o];
  }

  // epilogue: D row = w*16 + lg*4 + q, col = cf*16 + o
  #pragma unroll
  for (int q = 0; q < 4; ++q){
    int node = n0 + w*16 + lg*4 + q;
    float v[8];
    #pragma unroll
    for (int cf = 0; cf < 8; ++cf) v[cf] = acc[cf][q];
    float pi[4], pj[4];
    #pragma unroll
    for (int hd = 0; hd < 4; ++hd){
      pi[hd] = v[2*hd]*ai0[hd] + v[2*hd+1]*ai1[hd];
      pj[hd] = v[2*hd]*aj0[hd] + v[2*hd+1]*aj1[hd];
    }
    #pragma unroll
    for (int sh = 1; sh < 16; sh <<= 1){
      #pragma unroll
      for (int hd = 0; hd < 4; ++hd){
        pi[hd] += __shfl_xor(pi[hd], sh);
        pj[hd] += __shfl_xor(pj[hd], sh);
      }
    }
    if (node < N){
      #pragma unroll
      for (int hd = 0; hd < 4; ++hd)
        h_pair[(size_t)node*64 + hd*16 + o] = pack_bf2(v[2*hd], v[2*hd+1]);
      if (o == 0){
        *(float4*)&s_i[(size_t)node*4] = make_float4(pi[0], pi[1], pi[2], pi[3]);
        *(float4*)&s_j[(size_t)node*4] = make_float4(pj[0], pj[1], pj[2], pj[3]);
      }
    }
  }
}

// ---------------- fused softmax + gram + weighted aggregation (round-6 proven, verbatim) ----------------
// lane l: head g=l>>4, slot o=l&15; owns channels 32g+o and 32g+16+o (h_pair layout).
// No __syncthreads in the node loop: LDS slices are wave-private, intra-wave order via lds_fence.

__global__ __launch_bounds__(256) void k_agg(const uint32* __restrict__ h_pair, const float* __restrict__ s_i,
                                             const float* __restrict__ s_j, const int* __restrict__ cnt,
                                             const int* __restrict__ bucket,
                                             const float* __restrict__ bias, float* __restrict__ out,
                                             float* __restrict__ gram_part, int N){
  __shared__ __align__(16) float al[4][SLOT*4];   // per-wave alpha[j][head]
  __shared__ int   cs[4][SLOT];                   // per-wave src*64 (pre-shifted)
  __shared__ float red[4][10];
  int t = threadIdx.x;
  int w = t >> 6, l = t & 63;
  int g = l >> 4, o = l & 15;
  float b0 = bias[32*g + o];
  float b1 = bias[32*g + 16 + o];
  float ga[10];
  #pragma unroll
  for (int p = 0; p < 10; ++p) ga[p] = 0.f;
  int TW = gridDim.x * 4;

  for (int n = blockIdx.x*4 + w; n < N; n += TW){
    int dc = cnt[n]; if (dc > SLOT-1) dc = SLOT-1;
    int d  = dc + 1;                               // + self loop (implicit, last slot)
    float4 si = *(const float4*)&s_i[(size_t)n*4];
    if (l < d){
      int src = (l < dc) ? bucket[(size_t)n*SLOT + l] : n;
      cs[w][l] = src << 6;                         // pre-multiplied h_pair row offset
      float4 sj = *(const float4*)&s_j[(size_t)src*4];
      float4 e;
      e.x = si.x + sj.x; e.y = si.y + sj.y; e.z = si.z + sj.z; e.w = si.w + sj.w;
      e.x = e.x >= 0.f ? e.x : 0.2f*e.x;
      e.y = e.y >= 0.f ? e.y : 0.2f*e.y;
      e.z = e.z >= 0.f ? e.z : 0.2f*e.z;
      e.w = e.w >= 0.f ? e.w : 0.2f*e.w;
      *(float4*)&al[w][l*4] = e;
    }
    lds_fence();
    // per-head softmax: 16 lanes per head, d <= 64 -> at most 4 strided slots
    float m = -3.4e38f;
    for (int j = o; j < d; j += 16) m = fmaxf(m, al[w][j*4 + g]);
    #pragma unroll
    for (int sh = 1; sh < 16; sh <<= 1) m = fmaxf(m, __shfl_xor(m, sh));
    float sum = 0.f;
    for (int j = o; j < d; j += 16){
      float v = __expf(al[w][j*4 + g] - m);
      al[w][j*4 + g] = v;
      sum += v;
    }
    #pragma unroll
    for (int sh = 1; sh < 16; sh <<= 1) sum += __shfl_xor(sum, sh);
    float r = 1.f/(sum + 1e-16f);
    for (int j = o; j < d; j += 16) al[w][j*4 + g] *= r;
    lds_fence();
    // gram partials (single shot: d <= 64)
    if (l < d){
      float4 a = *(const float4*)&al[w][l*4];
      ga[0] += a.x*a.x; ga[1] += a.x*a.y; ga[2] += a.x*a.z; ga[3] += a.x*a.w;
      ga[4] += a.y*a.y; ga[5] += a.y*a.z; ga[6] += a.y*a.w;
      ga[7] += a.z*a.z; ga[8] += a.z*a.w;
      ga[9] += a.w*a.w;
    }
    // weighted gather, 4-wide load batching (r6 measured optimum; 8-deep regressed, r13)
    float a0 = 0.f, a1 = 0.f;
    const float* alw = &al[w][0];
    const int*   csw = &cs[w][0];
    int j = 0;
    for (; j + 4 <= d; j += 4){
      int   o0 = csw[j+0], o1 = csw[j+1], o2 = csw[j+2], o3 = csw[j+3];
      float w0 = alw[(j+0)*4 + g], w1 = alw[(j+1)*4 + g];
      float w2 = alw[(j+2)*4 + g], w3 = alw[(j+3)*4 + g];
      uint32 v0 = h_pair[(size_t)(uint32)(o0 + l)];
      uint32 v1 = h_pair[(size_t)(uint32)(o1 + l)];
      uint32 v2 = h_pair[(size_t)(uint32)(o2 + l)];
      uint32 v3 = h_pair[(size_t)(uint32)(o3 + l)];
      a0 += w0 * __uint_as_float(v0 << 16);  a1 += w0 * __uint_as_float(v0 & 0xffff0000u);
      a0 += w1 * __uint_as_float(v1 << 16);  a1 += w1 * __uint_as_float(v1 & 0xffff0000u);
      a0 += w2 * __uint_as_float(v2 << 16);  a1 += w2 * __uint_as_float(v2 & 0xffff0000u);
      a0 += w3 * __uint_as_float(v3 << 16);  a1 += w3 * __uint_as_float(v3 & 0xffff0000u);
    }
    for (; j < d; ++j){
      float aw = alw[j*4 + g];
      uint32 v = h_pair[(size_t)(uint32)(csw[j] + l)];
      a0 += aw * __uint_as_float(v << 16);
      a1 += aw * __uint_as_float(v & 0xffff0000u);
    }
    out[(size_t)n*128 + 32*g + o]      = a0 + b0;
    out[(size_t)n*128 + 32*g + 16 + o] = a1 + b1;
    lds_fence();                                   // WAR guard before next staging write
  }
  __syncthreads();
  #pragma unroll
  for (int p = 0; p < 10; ++p){
    float v = ga[p];
    #pragma unroll
    for (int sh = 1; sh < 64; sh <<= 1) v += __shfl_xor(v, sh);
    ga[p] = v;
  }
  if (l == 0){
    #pragma unroll
    for (int p = 0; p < 10; ++p) red[w][p] = ga[p];
  }
  __syncthreads();
  if (t == 0){
    #pragma unroll
    for (int p = 0; p < 10; ++p)
      gram_part[(size_t)blockIdx.x*10 + p] = red[0][p] + red[1][p] + red[2][p] + red[3][p];
  }
}

// ---------------- gram reduce + diversity loss ----------------

__global__ __launch_bounds__(256) void k_final(const float* __restrict__ gram_part, int nparts,
                                               float* __restrict__ loss){
  __shared__ float red[4][10];
  int t = threadIdx.x;
  float acc[10];
  #pragma unroll
  for (int p = 0; p < 10; ++p) acc[p] = 0.f;
  for (int i = t; i < nparts; i += 256){
    #pragma unroll
    for (int p = 0; p < 10; ++p) acc[p] += gram_part[(size_t)i*10 + p];
  }
  #pragma unroll
  for (int p = 0; p < 10; ++p){
    float v = acc[p];
    #pragma unroll
    for (int sh = 1; sh < 64; sh <<= 1) v += __shfl_xor(v, sh);
    acc[p] = v;
  }
  if ((t & 63) == 0){
    #pragma unroll
    for (int p = 0; p < 10; ++p) red[t >> 6][p] = acc[p];
  }
  __syncthreads();
  if (t == 0){
    float gs[10];
    #pragma unroll
    for (int p = 0; p < 10; ++p) gs[p] = red[0][p] + red[1][p] + red[2][p] + red[3][p];
    float G[4][4];
    G[0][0]=gs[0]; G[0][1]=gs[1]; G[0][2]=gs[2]; G[0][3]=gs[3];
    G[1][0]=gs[1]; G[1][1]=gs[4]; G[1][2]=gs[5]; G[1][3]=gs[6];
    G[2][0]=gs[2]; G[2][1]=gs[5]; G[2][2]=gs[7]; G[2][3]=gs[8];
    G[3][0]=gs[3]; G[3][1]=gs[6]; G[3][2]=gs[8]; G[3][3]=gs[9];
    float nr[4];
    for (int i = 0; i < 4; ++i) nr[i] = sqrtf(G[i][i]);
    float ssum = 0.f;
    for (int i = 0; i < 4; ++i)
      for (int j = 0; j < 4; ++j)
        if (i != j) ssum += G[i][j] / fmaxf(nr[i]*nr[j], 1e-8f);
    loss[0] = ssum * (0.1f/16.f);
  }
}

// ---------------- launch ----------------

extern "C" void kernel_launch(void* const* d_in, const int* in_sizes, int n_in,
                              void* d_out, int out_size, void* d_ws, size_t ws_size,
                              hipStream_t stream){
  const float* x    = (const float*)d_in[0];
  const int*   edge = (const int*)d_in[1];
  const float* W    = (const float*)d_in[2];
  const float* att  = (const float*)d_in[3];
  const float* bias = (const float*)d_in[4];
  int N = in_sizes[0] / 128;
  int E = in_sizes[1] / 2;
  const int* row = edge;       // destinations
  const int* col = edge + E;   // sources
  float* out  = (float*)d_out;
  float* loss = out + (size_t)N*HC;

  char* wsb = (char*)d_ws;
  size_t off = 0;
  auto alloc = [&](size_t bytes)->void*{
    size_t o = (off + 255) & ~(size_t)255;
    off = o + bytes;
    return (void*)(wsb + o);
  };
  uint32* h_pair   = (uint32*)alloc((size_t)N*64*sizeof(uint32));
  float* s_i       = (float*)alloc((size_t)N*4*sizeof(float));
  float* s_j       = (float*)alloc((size_t)N*4*sizeof(float));
  int*   cnt       = (int*)alloc((size_t)N*sizeof(int));
  int*   bucket    = (int*)alloc((size_t)N*SLOT*sizeof(int));
  float* gram_part = (float*)alloc((size_t)AGG_BLOCKS*10*sizeof(float));
  (void)ws_size; (void)n_in; (void)out_size;

  hipMemsetAsync(cnt, 0, (size_t)N*sizeof(int), stream);
  k_fill<<<CHUNKS*NPART,256,0,stream>>>(row, col, cnt, bucket, E, N);
  int GB = (N+63)/64;
  k_gemm<<<GB,256,0,stream>>>(x, W, att, h_pair, s_i, s_j, N);
  k_agg<<<AGG_BLOCKS,256,0,stream>>>(h_pair, s_i, s_j, cnt, bucket, bias, out, gram_part, N);
  k_final<<<1,256,0,stream>>>(gram_part, AGG_BLOCKS, loss);
}